// Round 4
// baseline (36.735 us; speedup 1.0000x reference)
//
#include <hip/hip_runtime.h>
#include <hip/hip_bf16.h>

#define DD 128

typedef __attribute__((ext_vector_type(8))) short short8;
typedef __attribute__((ext_vector_type(4))) float f32x4;

typedef __attribute__((address_space(1))) const void gvoid_t;
typedef __attribute__((address_space(3))) void svoid_t;
#define GLOAD_LDS16(g, s) __builtin_amdgcn_global_load_lds((gvoid_t*)(g), (svoid_t*)(s), 16, 0, 0)

__device__ __forceinline__ unsigned pack2(float a, float b) {
    __hip_bfloat162 h = __float22bfloat162_rn(make_float2(a, b));  // v_cvt_pk_bf16_f32
    unsigned u;
    __builtin_memcpy(&u, &h, 4);
    return u;
}

// ---------- prep: centers -> swizzled bf16 tiles in ws + csq_half ----------
// 8 threads per col: (col, q=dim-quarter, jh=half of quarter). Pad cols: 0 / 1e30.
__global__ void prep_centers(const float* __restrict__ ctr,
                             unsigned char* __restrict__ wsB,
                             float* __restrict__ csqh, int C, int Cpad) {
    int gid = blockIdx.x * 256 + threadIdx.x;
    int col = gid >> 3, q = (gid >> 1) & 3, jh = gid & 1;
    if (col >= Cpad) return;
    const float* src = ctr + (size_t)col * DD + q * 32;
    const int r = col & 127;
    const unsigned base = (unsigned)(col >> 7) * 32768u + (unsigned)r * 256u;
    const unsigned sw = ((unsigned)r & 7u) << 4;
    float cs = 0.f;
    #pragma unroll
    for (int jj = 0; jj < 2; ++jj) {
        int j = jh * 2 + jj;
        float4 v0 = make_float4(0.f,0.f,0.f,0.f), v1 = v0;
        if (col < C) {
            v0 = *(const float4*)(src + j * 8);
            v1 = *(const float4*)(src + j * 8 + 4);
        }
        cs = fmaf(v0.x,v0.x,cs); cs = fmaf(v0.y,v0.y,cs);
        cs = fmaf(v0.z,v0.z,cs); cs = fmaf(v0.w,v0.w,cs);
        cs = fmaf(v1.x,v1.x,cs); cs = fmaf(v1.y,v1.y,cs);
        cs = fmaf(v1.z,v1.z,cs); cs = fmaf(v1.w,v1.w,cs);
        uint4 w;
        w.x = pack2(v0.x, v0.y); w.y = pack2(v0.z, v0.w);
        w.z = pack2(v1.x, v1.y); w.w = pack2(v1.z, v1.w);
        *(uint4*)(wsB + base + ((((unsigned)q * 4u + j) * 16u) ^ sw)) = w;
    }
    cs += __shfl_xor(cs, 1); cs += __shfl_xor(cs, 2); cs += __shfl_xor(cs, 4);
    if ((gid & 7) == 0) csqh[col] = (col < C) ? 0.5f * cs : 1e30f;
}

// ---------- main: 64 rows/block x all cols, pipelined staging, atomic finish ----------
__global__ __launch_bounds__(256, 2) void center_mfma(
    const float* __restrict__ emb, const int* __restrict__ tgt,
    const float* __restrict__ ctr, const unsigned char* __restrict__ wsB,
    const float* __restrict__ csqh, unsigned long long* __restrict__ ctl,
    float* __restrict__ out, int C, int NT, double diagSub, double invDenom)
{
    __shared__ uint4 sA4[1024];    // 64 rows x 256 B (bf16, swizzled)
    __shared__ uint4 sB4[2048];    // 128 cols x 256 B
    __shared__ float sRT[64];
    __shared__ float sRed[4];
    unsigned char* sAb = (unsigned char*)sA4;
    unsigned char* sBb = (unsigned char*)sB4;

    const int t = threadIdx.x;
    const int row0 = blockIdx.x * 64;

    // ---- stage A (fp32 -> bf16 swizzled) + per-row rt_half ----
    {
        const int r = t >> 2, q = t & 3;
        const float* srcE = emb + (size_t)(row0 + r) * DD + q * 32;
        const int y = tgt[row0 + r];
        const float* srcC = ctr + (size_t)y * DD + q * 32;
        float se = 0.f, sd = 0.f;
        #pragma unroll
        for (int j = 0; j < 4; ++j) {
            float4 e0 = *(const float4*)(srcE + j * 8);
            float4 e1 = *(const float4*)(srcE + j * 8 + 4);
            float4 c0 = *(const float4*)(srcC + j * 8);
            float4 c1 = *(const float4*)(srcC + j * 8 + 4);
            se = fmaf(e0.x,e0.x,se); se = fmaf(e0.y,e0.y,se);
            se = fmaf(e0.z,e0.z,se); se = fmaf(e0.w,e0.w,se);
            se = fmaf(e1.x,e1.x,se); se = fmaf(e1.y,e1.y,se);
            se = fmaf(e1.z,e1.z,se); se = fmaf(e1.w,e1.w,se);
            float d;
            d = e0.x-c0.x; sd = fmaf(d,d,sd);  d = e0.y-c0.y; sd = fmaf(d,d,sd);
            d = e0.z-c0.z; sd = fmaf(d,d,sd);  d = e0.w-c0.w; sd = fmaf(d,d,sd);
            d = e1.x-c1.x; sd = fmaf(d,d,sd);  d = e1.y-c1.y; sd = fmaf(d,d,sd);
            d = e1.z-c1.z; sd = fmaf(d,d,sd);  d = e1.w-c1.w; sd = fmaf(d,d,sd);
            uint4 wv;
            wv.x = pack2(e0.x, e0.y); wv.y = pack2(e0.z, e0.w);
            wv.z = pack2(e1.x, e1.y); wv.w = pack2(e1.z, e1.w);
            unsigned off = (unsigned)r * 256u +
                ((((unsigned)q * 4u + j) * 16u) ^ (((unsigned)r & 7u) << 4));
            *(uint4*)(sAb + off) = wv;
        }
        se += __shfl_xor(se, 1); se += __shfl_xor(se, 2);
        sd += __shfl_xor(sd, 1); sd += __shfl_xor(sd, 2);
        if (q == 0) sRT[r] = 0.5f * (1.0f + sd - se);
    }
    __syncthreads();

    const int l  = t & 63;
    const int w  = t >> 6;        // wave id: owns cols w*32..w*32+31 of each tile
    const int li = l & 15;
    const int lh = l >> 4;        // 0..3
    const unsigned swz = ((unsigned)li & 7u) << 4;

    // hoist A fragments (reused across all col tiles): k = 8*lh + e
    short8 aF[4][4];
    #pragma unroll
    for (int mf = 0; mf < 4; ++mf)
        #pragma unroll
        for (int ks = 0; ks < 4; ++ks)
            aF[mf][ks] = *(const short8*)(sAb + (unsigned)(li + 16*mf) * 256u +
                                          (((unsigned)(16*lh + 64*ks)) ^ swz));
    float rtv[16];
    #pragma unroll
    for (int mf = 0; mf < 4; ++mf)
        #pragma unroll
        for (int rr = 0; rr < 4; ++rr)
            rtv[mf*4+rr] = sRT[16*mf + 4*lh + rr];

    // ---- pipelined prologue: issue stage(0) + cq(0) ----
    #pragma unroll
    for (int i = 0; i < 8; ++i) {
        unsigned off = (unsigned)(i * 256 + t) * 16u;
        GLOAD_LDS16(wsB + off, sBb + off);
    }
    float cqA = csqh[w*32 + li];
    float cqB = csqh[w*32 + 16 + li];

    float tsum = 0.f;

    for (int nt = 0; nt < NT; ++nt) {
        __syncthreads();      // drains vmcnt: stage(nt) + cq(nt) visible

        const float cq0 = cqA, cq1 = cqB;

        // B fragments of tile nt -> registers
        short8 bF0[4], bF1[4];
        #pragma unroll
        for (int ks = 0; ks < 4; ++ks) {
            unsigned kof = ((unsigned)(16*lh + 64*ks)) ^ swz;
            bF0[ks] = *(const short8*)(sBb + (unsigned)(li + 32*w) * 256u + kof);
            bF1[ks] = *(const short8*)(sBb + (unsigned)(li + 16 + 32*w) * 256u + kof);
        }
        __syncthreads();      // drains lgkm: all reads in regs; sB free to overwrite

        if (nt + 1 < NT) {    // issue next tile's staging under this tile's compute
            const unsigned char* g = wsB + (size_t)(nt + 1) * 32768;
            #pragma unroll
            for (int i = 0; i < 8; ++i) {
                unsigned off = (unsigned)(i * 256 + t) * 16u;
                GLOAD_LDS16(g + off, sBb + off);
            }
            cqA = csqh[(nt+1)*128 + w*32 + li];
            cqB = csqh[(nt+1)*128 + w*32 + 16 + li];
        }

        // C-init: 0.5*(1 + dis_intra - e_sq) - 0.5*c_sq  (pad cols -> -1e30)
        f32x4 acc[4][2];
        #pragma unroll
        for (int mf = 0; mf < 4; ++mf)
            #pragma unroll
            for (int rr = 0; rr < 4; ++rr) {
                acc[mf][0][rr] = rtv[mf*4+rr] - cq0;
                acc[mf][1][rr] = rtv[mf*4+rr] - cq1;
            }

        #pragma unroll
        for (int ks = 0; ks < 4; ++ks)
            #pragma unroll
            for (int mf = 0; mf < 4; ++mf) {
                acc[mf][0] = __builtin_amdgcn_mfma_f32_16x16x32_bf16(aF[mf][ks], bF0[ks], acc[mf][0], 0, 0, 0);
                acc[mf][1] = __builtin_amdgcn_mfma_f32_16x16x32_bf16(aF[mf][ks], bF1[ks], acc[mf][1], 0, 0, 0);
            }

        // epilogue: sum += 2*relu(acc)
        float s0 = 0.f, s1 = 0.f;
        #pragma unroll
        for (int mf = 0; mf < 4; ++mf)
            #pragma unroll
            for (int rr = 0; rr < 4; ++rr) {
                s0 = fmaf(2.0f, fmaxf(acc[mf][0][rr], 0.f), s0);
                s1 = fmaf(2.0f, fmaxf(acc[mf][1][rr], 0.f), s1);
            }
        tsum += s0 + s1;
    }

    // ---- block reduction + deterministic fixed-point atomic finish ----
    float s = tsum;
    #pragma unroll
    for (int off = 32; off; off >>= 1) s += __shfl_down(s, off);
    if (l == 0) sRed[w] = s;
    __syncthreads();
    if (t == 0) {
        float bs = sRed[0] + sRed[1] + sRed[2] + sRed[3];     // >= 0 always
        unsigned long long q = (unsigned long long)((double)bs * 4096.0 + 0.5);
        atomicAdd(&ctl[0], q);
        __threadfence();
        unsigned old = atomicAdd((unsigned*)&ctl[1], 1u);
        if (old == (unsigned)gridDim.x - 1u) {
            unsigned long long tot = atomicAdd(&ctl[0], 0ULL);  // coherent read
            out[0] = (float)(((double)tot * (1.0 / 4096.0) - diagSub) * invDenom);
        }
    }
}

extern "C" void kernel_launch(void* const* d_in, const int* in_sizes, int n_in,
                              void* d_out, int out_size, void* d_ws, size_t ws_size,
                              hipStream_t stream) {
    const float* emb = (const float*)d_in[0];
    const int*   tgt = (const int*)d_in[1];
    const float* ctr = (const float*)d_in[2];

    const int B = in_sizes[1];                 // 32768
    const int C = in_sizes[2] / DD;            // 1000
    const int NT = (C + 127) / 128;            // 8
    const int Cpad = NT * 128;                 // 1024
    const int nblk = B / 64;                   // 512

    unsigned char* wsB = (unsigned char*)d_ws;                       // NT*32 KB
    float* csqh = (float*)(wsB + (size_t)NT * 32768);                // [Cpad]
    unsigned long long* ctl = (unsigned long long*)(csqh + Cpad);    // acc, cnt

    (void)hipMemsetAsync(ctl, 0, 16, stream);
    prep_centers<<<(Cpad * 8) / 256, 256, 0, stream>>>(ctr, wsB, csqh, C, Cpad);
    center_mfma<<<nblk, 256, 0, stream>>>(emb, tgt, ctr, wsB, csqh, ctl,
                                          (float*)d_out, C, NT,
                                          (double)B,
                                          1.0 / ((double)B * (double)(C - 1)));
}

// Round 5
// 35.160 us; speedup vs baseline: 1.0448x; 1.0448x over previous
//
#include <hip/hip_runtime.h>
#include <hip/hip_bf16.h>

#define DD 128
#define NTC 8           // number of 128-col tiles (C=1000 -> Cpad=1024)

typedef __attribute__((ext_vector_type(8))) short short8;
typedef __attribute__((ext_vector_type(4))) float f32x4;

typedef __attribute__((address_space(1))) const void gvoid_t;
typedef __attribute__((address_space(3))) void svoid_t;
#define GLOAD_LDS16(g, s) __builtin_amdgcn_global_load_lds((gvoid_t*)(g), (svoid_t*)(s), 16, 0, 0)

__device__ __forceinline__ unsigned pack2(float a, float b) {
    __hip_bfloat162 h = __float22bfloat162_rn(make_float2(a, b));  // v_cvt_pk_bf16_f32
    unsigned u;
    __builtin_memcpy(&u, &h, 4);
    return u;
}

// ---------- prep: centers -> swizzled bf16 tiles in ws + csq_half; zero ctl ----------
// 8 threads per col: (col, q=dim-quarter, jh=half). Pad cols: 0 / 1e30.
__global__ void prep_centers(const float* __restrict__ ctr,
                             unsigned char* __restrict__ wsB,
                             float* __restrict__ csqh,
                             unsigned long long* __restrict__ ctl,
                             int C, int Cpad) {
    int gid = blockIdx.x * 256 + threadIdx.x;
    if (gid == 0) { ctl[0] = 0ULL; ctl[1] = 0ULL; }   // visible to main at kernel boundary
    int col = gid >> 3, q = (gid >> 1) & 3, jh = gid & 1;
    if (col >= Cpad) return;
    const float* src = ctr + (size_t)col * DD + q * 32;
    const int r = col & 127;
    const unsigned base = (unsigned)(col >> 7) * 32768u + (unsigned)r * 256u;
    const unsigned sw = ((unsigned)r & 7u) << 4;
    float cs = 0.f;
    #pragma unroll
    for (int jj = 0; jj < 2; ++jj) {
        int j = jh * 2 + jj;
        float4 v0 = make_float4(0.f,0.f,0.f,0.f), v1 = v0;
        if (col < C) {
            v0 = *(const float4*)(src + j * 8);
            v1 = *(const float4*)(src + j * 8 + 4);
        }
        cs = fmaf(v0.x,v0.x,cs); cs = fmaf(v0.y,v0.y,cs);
        cs = fmaf(v0.z,v0.z,cs); cs = fmaf(v0.w,v0.w,cs);
        cs = fmaf(v1.x,v1.x,cs); cs = fmaf(v1.y,v1.y,cs);
        cs = fmaf(v1.z,v1.z,cs); cs = fmaf(v1.w,v1.w,cs);
        uint4 w;
        w.x = pack2(v0.x, v0.y); w.y = pack2(v0.z, v0.w);
        w.z = pack2(v1.x, v1.y); w.w = pack2(v1.z, v1.w);
        *(uint4*)(wsB + base + ((((unsigned)q * 4u + j) * 16u) ^ sw)) = w;
    }
    cs += __shfl_xor(cs, 1); cs += __shfl_xor(cs, 2); cs += __shfl_xor(cs, 4);
    if ((gid & 7) == 0) csqh[col] = (col < C) ? 0.5f * cs : 1e30f;
}

// ---------- main: 64 rows/block x 1024 cols, true pipelined staging, atomic finish ----------
__global__ __launch_bounds__(256, 2) void center_mfma(
    const float* __restrict__ emb, const int* __restrict__ tgt,
    const float* __restrict__ ctr, const unsigned char* __restrict__ wsB,
    const float* __restrict__ csqh, unsigned long long* __restrict__ ctl,
    float* __restrict__ out, double diagSub, double invDenom)
{
    __shared__ uint4 sA4[1024];    // 64 rows x 256 B (bf16, swizzled)
    __shared__ uint4 sB4[2048];    // 128 cols x 256 B
    __shared__ float sRT[64];
    __shared__ float sRed[4];
    unsigned char* sAb = (unsigned char*)sA4;
    unsigned char* sBb = (unsigned char*)sB4;

    const int t = threadIdx.x;
    const int row0 = blockIdx.x * 64;

    // ---- stage A (fp32 -> bf16 swizzled) + per-row rt_half ----
    {
        const int r = t >> 2, q = t & 3;
        const float* srcE = emb + (size_t)(row0 + r) * DD + q * 32;
        const int y = tgt[row0 + r];
        const float* srcC = ctr + (size_t)y * DD + q * 32;
        float se = 0.f, sd = 0.f;
        #pragma unroll
        for (int j = 0; j < 4; ++j) {
            float4 e0 = *(const float4*)(srcE + j * 8);
            float4 e1 = *(const float4*)(srcE + j * 8 + 4);
            float4 c0 = *(const float4*)(srcC + j * 8);
            float4 c1 = *(const float4*)(srcC + j * 8 + 4);
            se = fmaf(e0.x,e0.x,se); se = fmaf(e0.y,e0.y,se);
            se = fmaf(e0.z,e0.z,se); se = fmaf(e0.w,e0.w,se);
            se = fmaf(e1.x,e1.x,se); se = fmaf(e1.y,e1.y,se);
            se = fmaf(e1.z,e1.z,se); se = fmaf(e1.w,e1.w,se);
            float d;
            d = e0.x-c0.x; sd = fmaf(d,d,sd);  d = e0.y-c0.y; sd = fmaf(d,d,sd);
            d = e0.z-c0.z; sd = fmaf(d,d,sd);  d = e0.w-c0.w; sd = fmaf(d,d,sd);
            d = e1.x-c1.x; sd = fmaf(d,d,sd);  d = e1.y-c1.y; sd = fmaf(d,d,sd);
            d = e1.z-c1.z; sd = fmaf(d,d,sd);  d = e1.w-c1.w; sd = fmaf(d,d,sd);
            uint4 wv;
            wv.x = pack2(e0.x, e0.y); wv.y = pack2(e0.z, e0.w);
            wv.z = pack2(e1.x, e1.y); wv.w = pack2(e1.z, e1.w);
            unsigned off = (unsigned)r * 256u +
                ((((unsigned)q * 4u + j) * 16u) ^ (((unsigned)r & 7u) << 4));
            *(uint4*)(sAb + off) = wv;
        }
        se += __shfl_xor(se, 1); se += __shfl_xor(se, 2);
        sd += __shfl_xor(sd, 1); sd += __shfl_xor(sd, 2);
        if (q == 0) sRT[r] = 0.5f * (1.0f + sd - se);
    }
    __syncthreads();

    const int l  = t & 63;
    const int w  = t >> 6;        // wave id: owns cols w*32..w*32+31 of each tile
    const int li = l & 15;
    const int lh = l >> 4;        // 0..3
    const unsigned swz = ((unsigned)li & 7u) << 4;

    // hoist A fragments (reused across all col tiles): k = 8*lh + e
    short8 aF[4][4];
    #pragma unroll
    for (int mf = 0; mf < 4; ++mf)
        #pragma unroll
        for (int ks = 0; ks < 4; ++ks)
            aF[mf][ks] = *(const short8*)(sAb + (unsigned)(li + 16*mf) * 256u +
                                          (((unsigned)(16*lh + 64*ks)) ^ swz));
    float rtv[16];
    #pragma unroll
    for (int mf = 0; mf < 4; ++mf)
        #pragma unroll
        for (int rr = 0; rr < 4; ++rr)
            rtv[mf*4+rr] = sRT[16*mf + 4*lh + rr];

    // ---- prologue: issue stage(0); hoist ALL csq values (keeps loop vmem = stages only) ----
    #pragma unroll
    for (int i = 0; i < 8; ++i) {
        unsigned off = (unsigned)(i * 256 + t) * 16u;
        GLOAD_LDS16(wsB + off, sBb + off);
    }
    float cqa[NTC], cqb[NTC];
    #pragma unroll
    for (int nt = 0; nt < NTC; ++nt) {
        cqa[nt] = csqh[nt*128 + w*32 + li];
        cqb[nt] = csqh[nt*128 + w*32 + 16 + li];
    }

    float tsum = 0.f;

    #pragma unroll
    for (int nt = 0; nt < NTC; ++nt) {
        __syncthreads();      // drains vmcnt: stage(nt) visible (covered by prev MFMA phase)

        // B fragments of tile nt -> registers
        short8 bF0[4], bF1[4];
        #pragma unroll
        for (int ks = 0; ks < 4; ++ks) {
            unsigned kof = ((unsigned)(16*lh + 64*ks)) ^ swz;
            bF0[ks] = *(const short8*)(sBb + (unsigned)(li + 32*w) * 256u + kof);
            bF1[ks] = *(const short8*)(sBb + (unsigned)(li + 16 + 32*w) * 256u + kof);
        }
        __syncthreads();      // lgkm drained; no vmem outstanding here -> cheap barrier

        if (nt + 1 < NTC) {   // issue next tile's staging under this tile's MFMA+epilogue
            const unsigned char* g = wsB + (size_t)(nt + 1) * 32768;
            #pragma unroll
            for (int i = 0; i < 8; ++i) {
                unsigned off = (unsigned)(i * 256 + t) * 16u;
                GLOAD_LDS16(g + off, sBb + off);
            }
        }

        // C-init: 0.5*(1 + dis_intra - e_sq) - 0.5*c_sq  (pad cols -> -1e30)
        f32x4 acc[4][2];
        #pragma unroll
        for (int mf = 0; mf < 4; ++mf)
            #pragma unroll
            for (int rr = 0; rr < 4; ++rr) {
                acc[mf][0][rr] = rtv[mf*4+rr] - cqa[nt];
                acc[mf][1][rr] = rtv[mf*4+rr] - cqb[nt];
            }

        #pragma unroll
        for (int ks = 0; ks < 4; ++ks)
            #pragma unroll
            for (int mf = 0; mf < 4; ++mf) {
                acc[mf][0] = __builtin_amdgcn_mfma_f32_16x16x32_bf16(aF[mf][ks], bF0[ks], acc[mf][0], 0, 0, 0);
                acc[mf][1] = __builtin_amdgcn_mfma_f32_16x16x32_bf16(aF[mf][ks], bF1[ks], acc[mf][1], 0, 0, 0);
            }

        // epilogue: sum += 2*relu(acc)
        float s0 = 0.f, s1 = 0.f;
        #pragma unroll
        for (int mf = 0; mf < 4; ++mf)
            #pragma unroll
            for (int rr = 0; rr < 4; ++rr) {
                s0 = fmaf(2.0f, fmaxf(acc[mf][0][rr], 0.f), s0);
                s1 = fmaf(2.0f, fmaxf(acc[mf][1][rr], 0.f), s1);
            }
        tsum += s0 + s1;
    }

    // ---- block reduction + deterministic fixed-point atomic finish ----
    float s = tsum;
    #pragma unroll
    for (int off = 32; off; off >>= 1) s += __shfl_down(s, off);
    if (l == 0) sRed[w] = s;
    __syncthreads();
    if (t == 0) {
        float bs = sRed[0] + sRed[1] + sRed[2] + sRed[3];     // >= 0 always
        unsigned long long q = (unsigned long long)((double)bs * 4096.0 + 0.5);
        atomicAdd(&ctl[0], q);
        __threadfence();
        unsigned old = atomicAdd((unsigned*)&ctl[1], 1u);
        if (old == (unsigned)gridDim.x - 1u) {
            unsigned long long tot = atomicAdd(&ctl[0], 0ULL);  // coherent read
            out[0] = (float)(((double)tot * (1.0 / 4096.0) - diagSub) * invDenom);
        }
    }
}

extern "C" void kernel_launch(void* const* d_in, const int* in_sizes, int n_in,
                              void* d_out, int out_size, void* d_ws, size_t ws_size,
                              hipStream_t stream) {
    const float* emb = (const float*)d_in[0];
    const int*   tgt = (const int*)d_in[1];
    const float* ctr = (const float*)d_in[2];

    const int B = in_sizes[1];                 // 32768
    const int C = in_sizes[2] / DD;            // 1000
    const int Cpad = NTC * 128;                // 1024
    const int nblk = B / 64;                   // 512

    unsigned char* wsB = (unsigned char*)d_ws;                       // NTC*32 KB
    float* csqh = (float*)(wsB + (size_t)NTC * 32768);               // [Cpad]
    unsigned long long* ctl = (unsigned long long*)(csqh + Cpad);    // acc, cnt

    prep_centers<<<(Cpad * 8) / 256, 256, 0, stream>>>(ctr, wsB, csqh, ctl, C, Cpad);
    center_mfma<<<nblk, 256, 0, stream>>>(emb, tgt, ctr, wsB, csqh, ctl,
                                          (float*)d_out,
                                          (double)B,
                                          1.0 / ((double)B * (double)(C - 1)));
}

// Round 6
// 28.101 us; speedup vs baseline: 1.3073x; 1.2512x over previous
//
#include <hip/hip_runtime.h>
#include <hip/hip_bf16.h>

#define DD 128
#define NTC 8           // number of 128-col tiles (C=1000 -> Cpad=1024)

typedef __attribute__((ext_vector_type(8))) short short8;
typedef __attribute__((ext_vector_type(4))) float f32x4;

typedef __attribute__((address_space(1))) const void gvoid_t;
typedef __attribute__((address_space(3))) void svoid_t;
#define GLOAD_LDS16(g, s) __builtin_amdgcn_global_load_lds((gvoid_t*)(g), (svoid_t*)(s), 16, 0, 0)

__device__ __forceinline__ unsigned pack2(float a, float b) {
    __hip_bfloat162 h = __float22bfloat162_rn(make_float2(a, b));  // v_cvt_pk_bf16_f32
    unsigned u;
    __builtin_memcpy(&u, &h, 4);
    return u;
}

// ---------- prep: centers -> swizzled bf16 tiles in ws + csq_half ----------
// 8 threads per col: (col, q=dim-quarter, jh=half). Pad cols: 0 / 1e30.
__global__ void prep_centers(const float* __restrict__ ctr,
                             unsigned char* __restrict__ wsB,
                             float* __restrict__ csqh,
                             int C, int Cpad) {
    int gid = blockIdx.x * 256 + threadIdx.x;
    int col = gid >> 3, q = (gid >> 1) & 3, jh = gid & 1;
    if (col >= Cpad) return;
    const float* src = ctr + (size_t)col * DD + q * 32;
    const int r = col & 127;
    const unsigned base = (unsigned)(col >> 7) * 32768u + (unsigned)r * 256u;
    const unsigned sw = ((unsigned)r & 7u) << 4;
    float cs = 0.f;
    #pragma unroll
    for (int jj = 0; jj < 2; ++jj) {
        int j = jh * 2 + jj;
        float4 v0 = make_float4(0.f,0.f,0.f,0.f), v1 = v0;
        if (col < C) {
            v0 = *(const float4*)(src + j * 8);
            v1 = *(const float4*)(src + j * 8 + 4);
        }
        cs = fmaf(v0.x,v0.x,cs); cs = fmaf(v0.y,v0.y,cs);
        cs = fmaf(v0.z,v0.z,cs); cs = fmaf(v0.w,v0.w,cs);
        cs = fmaf(v1.x,v1.x,cs); cs = fmaf(v1.y,v1.y,cs);
        cs = fmaf(v1.z,v1.z,cs); cs = fmaf(v1.w,v1.w,cs);
        uint4 w;
        w.x = pack2(v0.x, v0.y); w.y = pack2(v0.z, v0.w);
        w.z = pack2(v1.x, v1.y); w.w = pack2(v1.z, v1.w);
        *(uint4*)(wsB + base + ((((unsigned)q * 4u + j) * 16u) ^ sw)) = w;
    }
    cs += __shfl_xor(cs, 1); cs += __shfl_xor(cs, 2); cs += __shfl_xor(cs, 4);
    if ((gid & 7) == 0) csqh[col] = (col < C) ? 0.5f * cs : 1e30f;
}

// ---------- main: 64 rows/block x 1024 cols, pipelined staging, partials out ----------
__global__ __launch_bounds__(256, 2) void center_mfma(
    const float* __restrict__ emb, const int* __restrict__ tgt,
    const float* __restrict__ ctr, const unsigned char* __restrict__ wsB,
    const float* __restrict__ csqh, float* __restrict__ partials)
{
    __shared__ uint4 sA4[1024];    // 64 rows x 256 B (bf16, swizzled)
    __shared__ uint4 sB4[2048];    // 128 cols x 256 B
    __shared__ float sRT[64];
    __shared__ float sRed[4];
    unsigned char* sAb = (unsigned char*)sA4;
    unsigned char* sBb = (unsigned char*)sB4;

    const int t = threadIdx.x;
    const int row0 = blockIdx.x * 64;

    // ---- stage A (fp32 -> bf16 swizzled) + per-row rt_half ----
    {
        const int r = t >> 2, q = t & 3;
        const float* srcE = emb + (size_t)(row0 + r) * DD + q * 32;
        const int y = tgt[row0 + r];
        const float* srcC = ctr + (size_t)y * DD + q * 32;
        float se = 0.f, sd = 0.f;
        #pragma unroll
        for (int j = 0; j < 4; ++j) {
            float4 e0 = *(const float4*)(srcE + j * 8);
            float4 e1 = *(const float4*)(srcE + j * 8 + 4);
            float4 c0 = *(const float4*)(srcC + j * 8);
            float4 c1 = *(const float4*)(srcC + j * 8 + 4);
            se = fmaf(e0.x,e0.x,se); se = fmaf(e0.y,e0.y,se);
            se = fmaf(e0.z,e0.z,se); se = fmaf(e0.w,e0.w,se);
            se = fmaf(e1.x,e1.x,se); se = fmaf(e1.y,e1.y,se);
            se = fmaf(e1.z,e1.z,se); se = fmaf(e1.w,e1.w,se);
            float d;
            d = e0.x-c0.x; sd = fmaf(d,d,sd);  d = e0.y-c0.y; sd = fmaf(d,d,sd);
            d = e0.z-c0.z; sd = fmaf(d,d,sd);  d = e0.w-c0.w; sd = fmaf(d,d,sd);
            d = e1.x-c1.x; sd = fmaf(d,d,sd);  d = e1.y-c1.y; sd = fmaf(d,d,sd);
            d = e1.z-c1.z; sd = fmaf(d,d,sd);  d = e1.w-c1.w; sd = fmaf(d,d,sd);
            uint4 wv;
            wv.x = pack2(e0.x, e0.y); wv.y = pack2(e0.z, e0.w);
            wv.z = pack2(e1.x, e1.y); wv.w = pack2(e1.z, e1.w);
            unsigned off = (unsigned)r * 256u +
                ((((unsigned)q * 4u + j) * 16u) ^ (((unsigned)r & 7u) << 4));
            *(uint4*)(sAb + off) = wv;
        }
        se += __shfl_xor(se, 1); se += __shfl_xor(se, 2);
        sd += __shfl_xor(sd, 1); sd += __shfl_xor(sd, 2);
        if (q == 0) sRT[r] = 0.5f * (1.0f + sd - se);
    }
    __syncthreads();

    const int l  = t & 63;
    const int w  = t >> 6;        // wave id: owns cols w*32..w*32+31 of each tile
    const int li = l & 15;
    const int lh = l >> 4;        // 0..3
    const unsigned swz = ((unsigned)li & 7u) << 4;

    // hoist A fragments (reused across all col tiles): k = 8*lh + e
    short8 aF[4][4];
    #pragma unroll
    for (int mf = 0; mf < 4; ++mf)
        #pragma unroll
        for (int ks = 0; ks < 4; ++ks)
            aF[mf][ks] = *(const short8*)(sAb + (unsigned)(li + 16*mf) * 256u +
                                          (((unsigned)(16*lh + 64*ks)) ^ swz));
    float rtv[16];
    #pragma unroll
    for (int mf = 0; mf < 4; ++mf)
        #pragma unroll
        for (int rr = 0; rr < 4; ++rr)
            rtv[mf*4+rr] = sRT[16*mf + 4*lh + rr];

    // ---- prologue: issue stage(0) ----
    #pragma unroll
    for (int i = 0; i < 8; ++i) {
        unsigned off = (unsigned)(i * 256 + t) * 16u;
        GLOAD_LDS16(wsB + off, sBb + off);
    }

    float tsum = 0.f;

    #pragma unroll
    for (int nt = 0; nt < NTC; ++nt) {
        __syncthreads();      // drains vmcnt: stage(nt) visible (covered by prev MFMA phase)

        // early csq loads (L2-hit; retire via fine-grained vmcnt before acc-init)
        const float cq0 = csqh[nt*128 + w*32 + li];
        const float cq1 = csqh[nt*128 + w*32 + 16 + li];

        // B fragments of tile nt -> registers
        short8 bF0[4], bF1[4];
        #pragma unroll
        for (int ks = 0; ks < 4; ++ks) {
            unsigned kof = ((unsigned)(16*lh + 64*ks)) ^ swz;
            bF0[ks] = *(const short8*)(sBb + (unsigned)(li + 32*w) * 256u + kof);
            bF1[ks] = *(const short8*)(sBb + (unsigned)(li + 16 + 32*w) * 256u + kof);
        }
        __syncthreads();      // lgkm drained; sB free to overwrite

        if (nt + 1 < NTC) {   // issue next tile's staging under this tile's MFMA+epilogue
            const unsigned char* g = wsB + (size_t)(nt + 1) * 32768;
            #pragma unroll
            for (int i = 0; i < 8; ++i) {
                unsigned off = (unsigned)(i * 256 + t) * 16u;
                GLOAD_LDS16(g + off, sBb + off);
            }
        }

        // C-init: 0.5*(1 + dis_intra - e_sq) - 0.5*c_sq  (pad cols -> -1e30)
        f32x4 acc[4][2];
        #pragma unroll
        for (int mf = 0; mf < 4; ++mf)
            #pragma unroll
            for (int rr = 0; rr < 4; ++rr) {
                acc[mf][0][rr] = rtv[mf*4+rr] - cq0;
                acc[mf][1][rr] = rtv[mf*4+rr] - cq1;
            }

        #pragma unroll
        for (int ks = 0; ks < 4; ++ks)
            #pragma unroll
            for (int mf = 0; mf < 4; ++mf) {
                acc[mf][0] = __builtin_amdgcn_mfma_f32_16x16x32_bf16(aF[mf][ks], bF0[ks], acc[mf][0], 0, 0, 0);
                acc[mf][1] = __builtin_amdgcn_mfma_f32_16x16x32_bf16(aF[mf][ks], bF1[ks], acc[mf][1], 0, 0, 0);
            }

        // epilogue: sum += 2*relu(acc)
        float s0 = 0.f, s1 = 0.f;
        #pragma unroll
        for (int mf = 0; mf < 4; ++mf)
            #pragma unroll
            for (int rr = 0; rr < 4; ++rr) {
                s0 = fmaf(2.0f, fmaxf(acc[mf][0][rr], 0.f), s0);
                s1 = fmaf(2.0f, fmaxf(acc[mf][1][rr], 0.f), s1);
            }
        tsum += s0 + s1;
    }

    // ---- block reduction -> deterministic per-block partial ----
    float s = tsum;
    #pragma unroll
    for (int off = 32; off; off >>= 1) s += __shfl_down(s, off);
    if (l == 0) sRed[w] = s;
    __syncthreads();
    if (t == 0) partials[blockIdx.x] = sRed[0] + sRed[1] + sRed[2] + sRed[3];
}

// ---------- final reduction ----------
__global__ void reduce_k(const float* __restrict__ partials, int n,
                         float* __restrict__ out, double diagSub, double invDenom) {
    __shared__ double sRed[4];
    int t = threadIdx.x;
    double s = 0.0;
    for (int i = t; i < n; i += 256) s += (double)partials[i];
    #pragma unroll
    for (int off = 32; off; off >>= 1) s += __shfl_down(s, off);
    if ((t & 63) == 0) sRed[t >> 6] = s;
    __syncthreads();
    if (t == 0) out[0] = (float)(((sRed[0]+sRed[1]+sRed[2]+sRed[3]) - diagSub) * invDenom);
}

extern "C" void kernel_launch(void* const* d_in, const int* in_sizes, int n_in,
                              void* d_out, int out_size, void* d_ws, size_t ws_size,
                              hipStream_t stream) {
    const float* emb = (const float*)d_in[0];
    const int*   tgt = (const int*)d_in[1];
    const float* ctr = (const float*)d_in[2];

    const int B = in_sizes[1];                 // 32768
    const int C = in_sizes[2] / DD;            // 1000
    const int Cpad = NTC * 128;                // 1024
    const int nblk = B / 64;                   // 512

    unsigned char* wsB = (unsigned char*)d_ws;                       // NTC*32 KB
    float* csqh = (float*)(wsB + (size_t)NTC * 32768);               // [Cpad]
    float* partials = csqh + Cpad;                                   // [nblk]

    prep_centers<<<(Cpad * 8) / 256, 256, 0, stream>>>(ctr, wsB, csqh, C, Cpad);
    center_mfma<<<nblk, 256, 0, stream>>>(emb, tgt, ctr, wsB, csqh, partials);
    reduce_k<<<1, 256, 0, stream>>>(partials, nblk, (float*)d_out,
                                    (double)B,
                                    1.0 / ((double)B * (double)(C - 1)));
}